// Round 13
// baseline (95.101 us; speedup 1.0000x reference)
//
#include <hip/hip_runtime.h>
#include <hip/hip_fp16.h>

// out = A @ x, A sparse COO (rows, cols, edge_vals), x [N,64] f32.
//
// Pipeline:
//   0. convert_x: x f32 -> fp16 workspace copy (halves gather bytes+footprint;
//      round 12 proved bytes are NOT the binding constraint, but fp16 keeps BW
//      margin free; absmax 0.0625 << 0.285 threshold).
//   1. chunk_sort (512 thr): one block per 4096-edge chunk, bucket-sorts into
//      its private pairs[] region (full-line writes), emits u16 offset table.
//   2. transpose_table: [ch][b] -> [b][ch] for contiguous descriptor reads.
//   3. sort_reduce: one block per 64-row bucket. Parallel pure-copy staging ->
//      LDS hist -> shfl scan -> scatter FULL pairs to srt (no u16 indirection
//      in the hot loop) -> FOUR-rows-in-flight 4-wide REGISTER reduce
//      (16 outstanding gathers/wave; round 9->10 showed 4->8 in flight =
//      86->62us; requests, not bytes, are the currency per round 12).
//
// Hard-won rules: inner loops accumulate in REGISTERS; never make an LDS
// atomic data-dependent on a global load in a hot loop (round 6 = 550us);
// staging must be wide/parallel (round 8 = 109us); global scatter writes
// must be block-private regions (rounds 3-5: WRITE = E*64B); occupancy via
// bucket-split is a wash (round 11).

#define D_FEAT   64
#define RPB      64             // rows per bucket
#define RPB_BITS 6
#define COL_BITS 17             // col < 2^17; row-in-bucket in bits [17,23)
#define COL_MASK ((1u << COL_BITS) - 1)
#define CAP      1152           // LDS pair cap per bucket (mean 800, +12 sigma)
#define NB_MAX   1600           // max buckets (1563 used)
#define NCH_MAX  400            // max chunks (306 used at 4096)

// ---------------- fallback (round-1 kernel) ----------------
__global__ void spmv_coo_kernel(const float* __restrict__ x,
                                const int* __restrict__ rows,
                                const int* __restrict__ cols,
                                const float* __restrict__ ev,
                                float* __restrict__ out,
                                int n_edges) {
    const int lane = threadIdx.x & 63;
    const int wave_global = blockIdx.x * (blockDim.x >> 6) + (threadIdx.x >> 6);
    const int n_waves = gridDim.x * (blockDim.x >> 6);
    for (int e = wave_global; e < n_edges; e += n_waves) {
        atomicAdd(&out[rows[e] * D_FEAT + lane], ev[e] * x[cols[e] * D_FEAT + lane]);
    }
}

// ---------------- phase 0: x f32 -> fp16 ----------------
__global__ void __launch_bounds__(256) convert_x_kernel(
        const float4* __restrict__ x4, __half* __restrict__ xh, int n4) {
    int gid = blockIdx.x * blockDim.x + threadIdx.x;
    int stride = gridDim.x * blockDim.x;
    for (int i = gid; i < n4; i += stride) {
        float4 v = x4[i];
        __half2 h0 = __floats2half2_rn(v.x, v.y);
        __half2 h1 = __floats2half2_rn(v.z, v.w);
        ((__half2*)xh)[2 * i]     = h0;
        ((__half2*)xh)[2 * i + 1] = h1;
    }
}

// ------------- phase 1: per-chunk bucket sort (512 threads/chunk) ----------
__global__ void __launch_bounds__(512) chunk_sort_kernel(
        const int* __restrict__ rows, const int* __restrict__ cols,
        const float* __restrict__ ev,
        uint2* __restrict__ pairs, unsigned short* __restrict__ table,
        int n_edges, int nb, int ch_bits) {
    __shared__ int sh_cnt[NB_MAX];
    __shared__ int sh_off[NB_MAX];
    __shared__ int sb[512];
    const int t = threadIdx.x;
    const int ch = blockIdx.x;
    const int base = ch << ch_bits;
    const int cnt = min(1 << ch_bits, n_edges - base);

    for (int i = t; i < nb; i += 512) sh_cnt[i] = 0;
    __syncthreads();
    for (int i = t; i < cnt; i += 512)
        atomicAdd(&sh_cnt[rows[base + i] >> RPB_BITS], 1);
    __syncthreads();

    // hierarchical exclusive scan over nb bins
    const int items = (nb + 511) / 512;
    const int i0 = t * items;
    int s = 0;
    for (int j = 0; j < items; ++j) {
        int idx = i0 + j;
        if (idx < nb) s += sh_cnt[idx];
    }
    sb[t] = s;
    __syncthreads();
    for (int off = 1; off < 512; off <<= 1) {
        int tmp = (t >= off) ? sb[t - off] : 0;
        __syncthreads();
        sb[t] += tmp;
        __syncthreads();
    }
    int run = sb[t] - s;
    for (int j = 0; j < items; ++j) {
        int idx = i0 + j;
        if (idx < nb) { sh_off[idx] = run; run += sh_cnt[idx]; }
    }
    __syncthreads();

    // emit table row (u16 start offsets; entry nb = chunk count)
    unsigned short* trow = table + (size_t)ch * (nb + 1);
    for (int i = t; i < nb; i += 512) trow[i] = (unsigned short)sh_off[i];
    if (t == 0) trow[nb] = (unsigned short)cnt;
    __syncthreads();

    // place pass: block-private streaming region [base, base+cnt)
    for (int i = t; i < cnt; i += 512) {
        int r = rows[base + i];
        int bk = r >> RPB_BITS;
        int pos = atomicAdd(&sh_off[bk], 1);
        uint2 p;
        p.x = (unsigned)cols[base + i] | ((unsigned)(r & (RPB - 1)) << COL_BITS);
        p.y = __float_as_uint(ev[base + i]);
        pairs[base + pos] = p;
    }
}

// ------------- phase 2: table transpose [ch][b] -> [b][ch] -----------------
#define TT 64
__global__ void __launch_bounds__(256) transpose_table_kernel(
        const unsigned short* __restrict__ table,
        unsigned short* __restrict__ tableT,
        int nch, int ncols /* nb+1 */) {
    __shared__ unsigned short tile[TT][TT + 1];
    const int r0 = blockIdx.x * TT;   // chunk tile
    const int c0 = blockIdx.y * TT;   // bucket tile
    for (int idx = threadIdx.x; idx < TT * TT; idx += 256) {
        int r = idx >> 6, c = idx & 63;
        int ch = r0 + r, b = c0 + c;
        tile[r][c] = (ch < nch && b < ncols) ? table[(size_t)ch * ncols + b] : 0;
    }
    __syncthreads();
    for (int idx = threadIdx.x; idx < TT * TT; idx += 256) {
        int b = idx >> 6, c = idx & 63;
        int gb = c0 + b, gch = r0 + c;
        if (gb < ncols && gch < nch)
            tableT[(size_t)gb * nch + gch] = tile[c][b];
    }
}

// ------------- phase 3: per-bucket stage + pair sort + 16-wide reduce ------
template <typename XT>
__device__ __forceinline__ float xload(const XT* p);
template <> __device__ __forceinline__ float xload<float>(const float* p) { return *p; }
template <> __device__ __forceinline__ float xload<__half>(const __half* p) { return __half2float(*p); }

#define GATH(P) (__uint_as_float((P).y) * xload<XT>(xl + (int)((P).x & COL_MASK) * D_FEAT))

#define DRAIN(jX, eX, aX0, aX1)                                              \
    while (jX + 4 <= eX) {                                                   \
        uint2 q0 = srt[jX], q1 = srt[jX + 1], q2 = srt[jX + 2], q3 = srt[jX + 3]; \
        aX0 += GATH(q0); aX1 += GATH(q1); aX0 += GATH(q2); aX1 += GATH(q3);  \
        jX += 4;                                                             \
    }                                                                        \
    if (jX + 2 <= eX) {                                                      \
        uint2 q0 = srt[jX], q1 = srt[jX + 1];                                \
        aX0 += GATH(q0); aX1 += GATH(q1);                                    \
        jX += 2;                                                             \
    }                                                                        \
    if (jX < eX) {                                                           \
        uint2 q0 = srt[jX];                                                  \
        aX0 += GATH(q0);                                                     \
    }

template <typename XT>
__global__ void __launch_bounds__(256) sort_reduce_kernel(
        const XT* __restrict__ x,
        const uint2* __restrict__ pairs,
        const unsigned short* __restrict__ table,
        const unsigned short* __restrict__ tableT,
        float* __restrict__ out,
        int n_rows, int nb, int nch, int ch_bits, int use_tt) {
    __shared__ uint2 buf[CAP];                 // 9.2 KB staged pairs
    __shared__ uint2 srt[CAP];                 // 9.2 KB row-sorted pairs
    __shared__ unsigned short scnt16[NCH_MAX];
    __shared__ unsigned short soff16[NCH_MAX];
    __shared__ unsigned short sst16[NCH_MAX];
    __shared__ int sb[256];
    __shared__ int hist[RPB + 1];
    __shared__ int lcur[RPB];
    const int t = threadIdx.x;
    const int lane = t & 63;
    const int w = t >> 6;
    const int b = blockIdx.x;

    // read run descriptors; thread t owns chunks [t*items, t*items+items)
    const int items = (nch + 255) / 256;
    const int c0 = t * items;
    int s = 0;
    if (use_tt) {
        const unsigned short* rowB0 = tableT + (size_t)b * nch;
        const unsigned short* rowB1 = tableT + (size_t)(b + 1) * nch;
        for (int j = 0; j < items; ++j) {
            int ch = c0 + j;
            if (ch < nch) {
                int o1 = rowB0[ch];
                int o2 = rowB1[ch];
                scnt16[ch] = (unsigned short)(o2 - o1);
                soff16[ch] = (unsigned short)o1;
                s += o2 - o1;
            }
        }
    } else {
        for (int j = 0; j < items; ++j) {
            int ch = c0 + j;
            if (ch < nch) {
                const unsigned short* trow = table + (size_t)ch * (nb + 1) + b;
                int o1 = trow[0];
                int o2 = trow[1];
                scnt16[ch] = (unsigned short)(o2 - o1);
                soff16[ch] = (unsigned short)o1;
                s += o2 - o1;
            }
        }
    }
    sb[t] = s;
    __syncthreads();
    for (int off = 1; off < 256; off <<= 1) {
        int tmp = (t >= off) ? sb[t - off] : 0;
        __syncthreads();
        sb[t] += tmp;
        __syncthreads();
    }
    const int total = sb[255];
    int run = sb[t] - s;
    for (int j = 0; j < items; ++j) {
        int ch = c0 + j;
        if (ch < nch) { sst16[ch] = (unsigned short)run; run += scnt16[ch]; }
    }
    if (t <= RPB) hist[t] = 0;
    __syncthreads();

    if (total <= CAP) {
        // stage runs: 4-lane group per chunk, PURE COPY (no LDS atomics)
        const int g = t >> 2;
        const int sl = t & 3;
        for (int ch = g; ch < nch; ch += 64) {
            const int c = scnt16[ch];
            const int cbase = (ch << ch_bits) + soff16[ch];
            const int dst = sst16[ch];
            for (int k = sl; k < c; k += 4)
                buf[dst + k] = pairs[cbase + k];
        }
        __syncthreads();
        // LDS-only histogram pass
        const unsigned* bufx = (const unsigned*)buf;
        for (int i = t; i < total; i += 256)
            atomicAdd(&hist[1 + (int)(bufx[2 * i] >> COL_BITS)], 1);
        __syncthreads();
        // wave 0: inclusive shfl-scan of hist[1..RPB] -> row_ptr
        if (w == 0) {
            int v = hist[1 + lane];
            for (int d = 1; d < 64; d <<= 1) {
                int n = __shfl_up(v, d);
                if (lane >= d) v += n;
            }
            hist[1 + lane] = v;
        }
        __syncthreads();
        if (w == 0) lcur[lane] = hist[lane];
        __syncthreads();
        // scatter FULL pairs into row-sorted srt (one LDS read in hot loop)
        for (int i = t; i < total; i += 256) {
            uint2 p = buf[i];
            int rl = (int)(p.x >> COL_BITS);
            int pos = atomicAdd(&lcur[rl], 1);
            srt[pos] = p;
        }
        __syncthreads();
        // reduce: wave w owns rows w+4q (q=0..15); FOUR rows concurrent,
        // 4-wide each -> 16 outstanding gathers per wave.
        const XT* xl = x + lane;
        for (int it = 0; it < 4; ++it) {
            const int rA = w + 16 * it;
            const int rB = rA + 4, rC = rA + 8, rD = rA + 12;
            int jA = hist[rA], eA = hist[rA + 1];
            int jB = hist[rB], eB = hist[rB + 1];
            int jC = hist[rC], eC = hist[rC + 1];
            int jD = hist[rD], eD = hist[rD + 1];
            float aA0 = 0.0f, aA1 = 0.0f, aB0 = 0.0f, aB1 = 0.0f;
            float aC0 = 0.0f, aC1 = 0.0f, aD0 = 0.0f, aD1 = 0.0f;
            while (jA + 4 <= eA && jB + 4 <= eB && jC + 4 <= eC && jD + 4 <= eD) {
                uint2 qa0 = srt[jA], qa1 = srt[jA + 1], qa2 = srt[jA + 2], qa3 = srt[jA + 3];
                uint2 qb0 = srt[jB], qb1 = srt[jB + 1], qb2 = srt[jB + 2], qb3 = srt[jB + 3];
                uint2 qc0 = srt[jC], qc1 = srt[jC + 1], qc2 = srt[jC + 2], qc3 = srt[jC + 3];
                uint2 qd0 = srt[jD], qd1 = srt[jD + 1], qd2 = srt[jD + 2], qd3 = srt[jD + 3];
                aA0 += GATH(qa0); aA1 += GATH(qa1); aA0 += GATH(qa2); aA1 += GATH(qa3);
                aB0 += GATH(qb0); aB1 += GATH(qb1); aB0 += GATH(qb2); aB1 += GATH(qb3);
                aC0 += GATH(qc0); aC1 += GATH(qc1); aC0 += GATH(qc2); aC1 += GATH(qc3);
                aD0 += GATH(qd0); aD1 += GATH(qd1); aD0 += GATH(qd2); aD1 += GATH(qd3);
                jA += 4; jB += 4; jC += 4; jD += 4;
            }
            DRAIN(jA, eA, aA0, aA1)
            DRAIN(jB, eB, aB0, aB1)
            DRAIN(jC, eC, aC0, aC1)
            DRAIN(jD, eD, aD0, aD1)
            const int rowA = b * RPB + rA;
            const int rowB = b * RPB + rB;
            const int rowC = b * RPB + rC;
            const int rowD = b * RPB + rD;
            if (rowA < n_rows) out[rowA * D_FEAT + lane] = aA0 + aA1;
            if (rowB < n_rows) out[rowB * D_FEAT + lane] = aB0 + aB1;
            if (rowC < n_rows) out[rowC * D_FEAT + lane] = aC0 + aC1;
            if (rowD < n_rows) out[rowD * D_FEAT + lane] = aD0 + aD1;
        }
    } else {
        // overflow bucket (statistically never at mean 800, cap 1152)
        for (int r = w; r < RPB; r += 4) {
            const int row = b * RPB + r;
            if (row < n_rows) out[row * D_FEAT + lane] = 0.0f;
        }
        __syncthreads();
        for (int ch = w; ch < nch; ch += 4) {
            const int cbase = (ch << ch_bits) + soff16[ch];
            const int c = scnt16[ch];
            for (int k = 0; k < c; ++k) {
                const uint2 p = pairs[cbase + k];
                const int rl = (int)(p.x >> COL_BITS);
                const int cc = (int)(p.x & COL_MASK);
                const float m = __uint_as_float(p.y) * xload<XT>(x + cc * D_FEAT + lane);
                const int row = b * RPB + rl;
                if (row < n_rows) atomicAdd(&out[row * D_FEAT + lane], m);
            }
        }
    }
}

extern "C" void kernel_launch(void* const* d_in, const int* in_sizes, int n_in,
                              void* d_out, int out_size, void* d_ws, size_t ws_size,
                              hipStream_t stream) {
    const float* x    = (const float*)d_in[1];
    const int*   rows = (const int*)d_in[2];
    const int*   cols = (const int*)d_in[3];
    const float* ev   = (const float*)d_in[4];
    float* out = (float*)d_out;
    const int n_edges = in_sizes[3];
    const int n_rows  = out_size / D_FEAT;
    const int n_x     = in_sizes[1];              // N*64 elements
    const int n_cols  = n_x / D_FEAT;
    const int nb = (n_rows + RPB - 1) / RPB;      // 1563 for N=100K

    // pick chunk size (prefer 4096); layer optional tableT and fp16-x copies
    int ch_bits = 0, nch = 0, use_tt = 0, use_fp16 = 0;
    size_t off_table = 0, off_tableT = 0, off_xh = 0;
    for (int cb = 12; cb <= 13 && ch_bits == 0; ++cb) {
        int nc = (n_edges + (1 << cb) - 1) >> cb;
        size_t pairs_b = ((size_t)nc << cb) * 8;
        size_t tab_b = (size_t)nc * (size_t)(nb + 1) * 2;
        if (nc <= NCH_MAX && ws_size >= pairs_b + tab_b) {
            ch_bits = cb; nch = nc;
            off_table = pairs_b;
            size_t cur = pairs_b + tab_b;
            if (ws_size >= cur + tab_b) {
                use_tt = 1;
                off_tableT = cur;
                cur += tab_b;
            }
            size_t xh_b = (size_t)n_x * 2;
            cur = (cur + 255) & ~(size_t)255;
            if (ws_size >= cur + xh_b && (n_x & 3) == 0) {
                use_fp16 = 1;
                off_xh = cur;
            }
        }
    }

    if (ch_bits == 0 || nb > NB_MAX || n_cols > (1 << COL_BITS) ||
        n_rows > (1 << COL_BITS)) {
        hipMemsetAsync(d_out, 0, (size_t)out_size * sizeof(float), stream);
        spmv_coo_kernel<<<4096, 256, 0, stream>>>(x, rows, cols, ev, out, n_edges);
        return;
    }

    uint2* pairs = (uint2*)d_ws;
    unsigned short* table  = (unsigned short*)((char*)d_ws + off_table);
    unsigned short* tableT = (unsigned short*)((char*)d_ws + off_tableT);
    __half* xh = (__half*)((char*)d_ws + off_xh);

    if (use_fp16)
        convert_x_kernel<<<1024, 256, 0, stream>>>((const float4*)x, xh, n_x / 4);

    chunk_sort_kernel<<<nch, 512, 0, stream>>>(rows, cols, ev, pairs, table,
                                               n_edges, nb, ch_bits);
    if (use_tt) {
        dim3 tg((nch + TT - 1) / TT, (nb + 1 + TT - 1) / TT);
        transpose_table_kernel<<<tg, 256, 0, stream>>>(table, tableT, nch, nb + 1);
    }
    if (use_fp16)
        sort_reduce_kernel<__half><<<nb, 256, 0, stream>>>(
            xh, pairs, table, tableT, out, n_rows, nb, nch, ch_bits, use_tt);
    else
        sort_reduce_kernel<float><<<nb, 256, 0, stream>>>(
            x, pairs, table, tableT, out, n_rows, nb, nch, ch_bits, use_tt);
}

// Round 14
// 81.879 us; speedup vs baseline: 1.1615x; 1.1615x over previous
//
#include <hip/hip_runtime.h>
#include <hip/hip_fp16.h>

// out = A @ x, A sparse COO (rows, cols, edge_vals), x [N,64] f32.
//
// Pipeline:
//   0. convert_x: x f32 -> fp16 workspace copy (absmax 0.0625 << 0.285 thr).
//   1. chunk_sort: one block per 4096-edge chunk, bucket-sorts into its
//      private pairs[] region (full-line writes), emits u16 offset table.
//   2. transpose_table: [ch][b] -> [b][ch] for contiguous descriptor reads.
//   3. sort_reduce_h2: one block per 64-row bucket. Staging/hist/scan/u16
//      sort as before; reduce processes TWO EDGES PER LOAD INSTRUCTION:
//      half-wave h (32 lanes) owns row-stream S=w*2+h, each lane covers 2
//      features via __half2 (one x-row = 128B = 32 lanes x 4B). Per wave
//      instruction: 2 gathers + 2 pair-reads -> VMEM/LDS instructions per
//      edge HALVED. Tests the per-instruction memory-pipe-throughput
//      hypothesis (rounds 10-13: reduce pinned ~60us across bytes/occ/ILP).
//
// Hard-won rules: inner loops accumulate in REGISTERS; never make an LDS
// atomic data-dependent on a global load in a hot loop (round 6 = 550us);
// staging must be wide/parallel (round 8 = 109us); global scatter writes
// must be block-private regions (rounds 3-5: WRITE = E*64B); occupancy via
// bucket-split is a wash (round 11); bytes are not the constraint (round 12).

#define D_FEAT   64
#define RPB      64             // rows per bucket
#define RPB_BITS 6
#define COL_BITS 17             // col < 2^17; row-in-bucket in bits [17,23)
#define COL_MASK ((1u << COL_BITS) - 1)
#define CAP      1152           // LDS pair cap per bucket (mean 800, +12 sigma)
#define NB_MAX   1600           // max buckets (1563 used)
#define NCH_MAX  400            // max chunks (306 used at 4096)

// ---------------- fallback (round-1 kernel) ----------------
__global__ void spmv_coo_kernel(const float* __restrict__ x,
                                const int* __restrict__ rows,
                                const int* __restrict__ cols,
                                const float* __restrict__ ev,
                                float* __restrict__ out,
                                int n_edges) {
    const int lane = threadIdx.x & 63;
    const int wave_global = blockIdx.x * (blockDim.x >> 6) + (threadIdx.x >> 6);
    const int n_waves = gridDim.x * (blockDim.x >> 6);
    for (int e = wave_global; e < n_edges; e += n_waves) {
        atomicAdd(&out[rows[e] * D_FEAT + lane], ev[e] * x[cols[e] * D_FEAT + lane]);
    }
}

// ---------------- phase 0: x f32 -> fp16 ----------------
__global__ void __launch_bounds__(256) convert_x_kernel(
        const float4* __restrict__ x4, __half* __restrict__ xh, int n4) {
    int gid = blockIdx.x * blockDim.x + threadIdx.x;
    int stride = gridDim.x * blockDim.x;
    for (int i = gid; i < n4; i += stride) {
        float4 v = x4[i];
        __half2 h0 = __floats2half2_rn(v.x, v.y);
        __half2 h1 = __floats2half2_rn(v.z, v.w);
        ((__half2*)xh)[2 * i]     = h0;
        ((__half2*)xh)[2 * i + 1] = h1;
    }
}

// ------------- phase 1: per-chunk bucket sort (one block per chunk) --------
__global__ void __launch_bounds__(256) chunk_sort_kernel(
        const int* __restrict__ rows, const int* __restrict__ cols,
        const float* __restrict__ ev,
        uint2* __restrict__ pairs, unsigned short* __restrict__ table,
        int n_edges, int nb, int ch_bits) {
    __shared__ int sh_cnt[NB_MAX];
    __shared__ int sh_off[NB_MAX];
    __shared__ int sb[256];
    const int t = threadIdx.x;
    const int ch = blockIdx.x;
    const int base = ch << ch_bits;
    const int cnt = min(1 << ch_bits, n_edges - base);

    for (int i = t; i < nb; i += 256) sh_cnt[i] = 0;
    __syncthreads();
    for (int i = t; i < cnt; i += 256)
        atomicAdd(&sh_cnt[rows[base + i] >> RPB_BITS], 1);
    __syncthreads();

    const int items = (nb + 255) / 256;
    const int i0 = t * items;
    int s = 0;
    for (int j = 0; j < items; ++j) {
        int idx = i0 + j;
        if (idx < nb) s += sh_cnt[idx];
    }
    sb[t] = s;
    __syncthreads();
    for (int off = 1; off < 256; off <<= 1) {
        int tmp = (t >= off) ? sb[t - off] : 0;
        __syncthreads();
        sb[t] += tmp;
        __syncthreads();
    }
    int run = sb[t] - s;
    for (int j = 0; j < items; ++j) {
        int idx = i0 + j;
        if (idx < nb) { sh_off[idx] = run; run += sh_cnt[idx]; }
    }
    __syncthreads();

    unsigned short* trow = table + (size_t)ch * (nb + 1);
    for (int i = t; i < nb; i += 256) trow[i] = (unsigned short)sh_off[i];
    if (t == 0) trow[nb] = (unsigned short)cnt;
    __syncthreads();

    for (int i = t; i < cnt; i += 256) {
        int r = rows[base + i];
        int bk = r >> RPB_BITS;
        int pos = atomicAdd(&sh_off[bk], 1);
        uint2 p;
        p.x = (unsigned)cols[base + i] | ((unsigned)(r & (RPB - 1)) << COL_BITS);
        p.y = __float_as_uint(ev[base + i]);
        pairs[base + pos] = p;
    }
}

// ------------- phase 2: table transpose [ch][b] -> [b][ch] -----------------
#define TT 64
__global__ void __launch_bounds__(256) transpose_table_kernel(
        const unsigned short* __restrict__ table,
        unsigned short* __restrict__ tableT,
        int nch, int ncols /* nb+1 */) {
    __shared__ unsigned short tile[TT][TT + 1];
    const int r0 = blockIdx.x * TT;
    const int c0 = blockIdx.y * TT;
    for (int idx = threadIdx.x; idx < TT * TT; idx += 256) {
        int r = idx >> 6, c = idx & 63;
        int ch = r0 + r, b = c0 + c;
        tile[r][c] = (ch < nch && b < ncols) ? table[(size_t)ch * ncols + b] : 0;
    }
    __syncthreads();
    for (int idx = threadIdx.x; idx < TT * TT; idx += 256) {
        int b = idx >> 6, c = idx & 63;
        int gb = c0 + b, gch = r0 + c;
        if (gb < ncols && gch < nch)
            tableT[(size_t)gb * nch + gch] = tile[c][b];
    }
}

// ---------- common prologue for reduce kernels (descriptors + stage) -------
// (macro-free: duplicated in both kernels for clarity)

// ------------- phase 3a: f32 fallback reduce (round-12 structure) ----------
__global__ void __launch_bounds__(256) sort_reduce_f32_kernel(
        const float* __restrict__ x,
        const uint2* __restrict__ pairs,
        const unsigned short* __restrict__ table,
        const unsigned short* __restrict__ tableT,
        float* __restrict__ out,
        int n_rows, int nb, int nch, int ch_bits, int use_tt) {
    __shared__ uint2 buf[CAP];
    __shared__ unsigned short srt16[CAP];
    __shared__ unsigned short scnt16[NCH_MAX];
    __shared__ unsigned short soff16[NCH_MAX];
    __shared__ unsigned short sst16[NCH_MAX];
    __shared__ int sb[256];
    __shared__ int hist[RPB + 1];
    __shared__ int lcur[RPB];
    const int t = threadIdx.x;
    const int lane = t & 63;
    const int w = t >> 6;
    const int b = blockIdx.x;

    const int items = (nch + 255) / 256;
    const int c0 = t * items;
    int s = 0;
    if (use_tt) {
        const unsigned short* rowB0 = tableT + (size_t)b * nch;
        const unsigned short* rowB1 = tableT + (size_t)(b + 1) * nch;
        for (int j = 0; j < items; ++j) {
            int ch = c0 + j;
            if (ch < nch) {
                int o1 = rowB0[ch], o2 = rowB1[ch];
                scnt16[ch] = (unsigned short)(o2 - o1);
                soff16[ch] = (unsigned short)o1;
                s += o2 - o1;
            }
        }
    } else {
        for (int j = 0; j < items; ++j) {
            int ch = c0 + j;
            if (ch < nch) {
                const unsigned short* trow = table + (size_t)ch * (nb + 1) + b;
                int o1 = trow[0], o2 = trow[1];
                scnt16[ch] = (unsigned short)(o2 - o1);
                soff16[ch] = (unsigned short)o1;
                s += o2 - o1;
            }
        }
    }
    sb[t] = s;
    __syncthreads();
    for (int off = 1; off < 256; off <<= 1) {
        int tmp = (t >= off) ? sb[t - off] : 0;
        __syncthreads();
        sb[t] += tmp;
        __syncthreads();
    }
    const int total = sb[255];
    int run = sb[t] - s;
    for (int j = 0; j < items; ++j) {
        int ch = c0 + j;
        if (ch < nch) { sst16[ch] = (unsigned short)run; run += scnt16[ch]; }
    }
    if (t <= RPB) hist[t] = 0;
    __syncthreads();

    if (total <= CAP) {
        const int g = t >> 2;
        const int sl = t & 3;
        for (int ch = g; ch < nch; ch += 64) {
            const int c = scnt16[ch];
            const int cbase = (ch << ch_bits) + soff16[ch];
            const int dst = sst16[ch];
            for (int k = sl; k < c; k += 4)
                buf[dst + k] = pairs[cbase + k];
        }
        __syncthreads();
        const unsigned* bufx = (const unsigned*)buf;
        for (int i = t; i < total; i += 256)
            atomicAdd(&hist[1 + (int)(bufx[2 * i] >> COL_BITS)], 1);
        __syncthreads();
        if (w == 0) {
            int v = hist[1 + lane];
            for (int d = 1; d < 64; d <<= 1) {
                int n = __shfl_up(v, d);
                if (lane >= d) v += n;
            }
            hist[1 + lane] = v;
        }
        __syncthreads();
        if (w == 0) lcur[lane] = hist[lane];
        __syncthreads();
        for (int i = t; i < total; i += 256) {
            int rl = (int)(bufx[2 * i] >> COL_BITS);
            int pos = atomicAdd(&lcur[rl], 1);
            srt16[pos] = (unsigned short)i;
        }
        __syncthreads();
        const float* xl = x + lane;
        for (int q = 0; q < RPB / 8; ++q) {
            const int rA = w + 8 * q;
            const int rB = rA + 4;
            int jA = hist[rA], eA = hist[rA + 1];
            int jB = hist[rB], eB = hist[rB + 1];
            float aA0 = 0.f, aA1 = 0.f, aB0 = 0.f, aB1 = 0.f;
            #define GF(P) (__uint_as_float((P).y) * xl[(int)((P).x & COL_MASK) * D_FEAT])
            while (jA + 4 <= eA && jB + 4 <= eB) {
                uint2 pa0 = buf[srt16[jA]], pa1 = buf[srt16[jA + 1]];
                uint2 pa2 = buf[srt16[jA + 2]], pa3 = buf[srt16[jA + 3]];
                uint2 pb0 = buf[srt16[jB]], pb1 = buf[srt16[jB + 1]];
                uint2 pb2 = buf[srt16[jB + 2]], pb3 = buf[srt16[jB + 3]];
                aA0 += GF(pa0); aA1 += GF(pa1); aA0 += GF(pa2); aA1 += GF(pa3);
                aB0 += GF(pb0); aB1 += GF(pb1); aB0 += GF(pb2); aB1 += GF(pb3);
                jA += 4; jB += 4;
            }
            while (jA + 2 <= eA) {
                uint2 p0 = buf[srt16[jA]], p1 = buf[srt16[jA + 1]];
                aA0 += GF(p0); aA1 += GF(p1); jA += 2;
            }
            while (jB + 2 <= eB) {
                uint2 p0 = buf[srt16[jB]], p1 = buf[srt16[jB + 1]];
                aB0 += GF(p0); aB1 += GF(p1); jB += 2;
            }
            if (jA < eA) { uint2 p0 = buf[srt16[jA]]; aA0 += GF(p0); }
            if (jB < eB) { uint2 p0 = buf[srt16[jB]]; aB0 += GF(p0); }
            #undef GF
            const int rowA = b * RPB + rA;
            const int rowB = b * RPB + rB;
            if (rowA < n_rows) out[rowA * D_FEAT + lane] = aA0 + aA1;
            if (rowB < n_rows) out[rowB * D_FEAT + lane] = aB0 + aB1;
        }
    } else {
        for (int r = w; r < RPB; r += 4) {
            const int row = b * RPB + r;
            if (row < n_rows) out[row * D_FEAT + lane] = 0.0f;
        }
        __syncthreads();
        for (int ch = w; ch < nch; ch += 4) {
            const int cbase = (ch << ch_bits) + soff16[ch];
            const int c = scnt16[ch];
            for (int k = 0; k < c; ++k) {
                const uint2 p = pairs[cbase + k];
                const int rl = (int)(p.x >> COL_BITS);
                const int cc = (int)(p.x & COL_MASK);
                const float m = __uint_as_float(p.y) * x[cc * D_FEAT + lane];
                const int row = b * RPB + rl;
                if (row < n_rows) atomicAdd(&out[row * D_FEAT + lane], m);
            }
        }
    }
}

// ------------- phase 3b: fp16 half2 DUAL-EDGE reduce -----------------------
// Half-wave h (lanes h*32..h*32+31) owns row-stream S = w*2+h; each lane
// covers features {2*hl, 2*hl+1} of its stream's current row. One load
// instruction gathers TWO x-rows (one per half) -> VMEM+LDS instr/edge halved.
__global__ void __launch_bounds__(256) sort_reduce_h2_kernel(
        const __half* __restrict__ x,
        const uint2* __restrict__ pairs,
        const unsigned short* __restrict__ table,
        const unsigned short* __restrict__ tableT,
        float* __restrict__ out,
        int n_rows, int nb, int nch, int ch_bits, int use_tt) {
    __shared__ uint2 buf[CAP];
    __shared__ unsigned short srt16[CAP];
    __shared__ unsigned short scnt16[NCH_MAX];
    __shared__ unsigned short soff16[NCH_MAX];
    __shared__ unsigned short sst16[NCH_MAX];
    __shared__ int sb[256];
    __shared__ int hist[RPB + 1];
    __shared__ int lcur[RPB];
    const int t = threadIdx.x;
    const int lane = t & 63;
    const int w = t >> 6;
    const int b = blockIdx.x;

    const int items = (nch + 255) / 256;
    const int c0 = t * items;
    int s = 0;
    if (use_tt) {
        const unsigned short* rowB0 = tableT + (size_t)b * nch;
        const unsigned short* rowB1 = tableT + (size_t)(b + 1) * nch;
        for (int j = 0; j < items; ++j) {
            int ch = c0 + j;
            if (ch < nch) {
                int o1 = rowB0[ch], o2 = rowB1[ch];
                scnt16[ch] = (unsigned short)(o2 - o1);
                soff16[ch] = (unsigned short)o1;
                s += o2 - o1;
            }
        }
    } else {
        for (int j = 0; j < items; ++j) {
            int ch = c0 + j;
            if (ch < nch) {
                const unsigned short* trow = table + (size_t)ch * (nb + 1) + b;
                int o1 = trow[0], o2 = trow[1];
                scnt16[ch] = (unsigned short)(o2 - o1);
                soff16[ch] = (unsigned short)o1;
                s += o2 - o1;
            }
        }
    }
    sb[t] = s;
    __syncthreads();
    for (int off = 1; off < 256; off <<= 1) {
        int tmp = (t >= off) ? sb[t - off] : 0;
        __syncthreads();
        sb[t] += tmp;
        __syncthreads();
    }
    const int total = sb[255];
    int run = sb[t] - s;
    for (int j = 0; j < items; ++j) {
        int ch = c0 + j;
        if (ch < nch) { sst16[ch] = (unsigned short)run; run += scnt16[ch]; }
    }
    if (t <= RPB) hist[t] = 0;
    __syncthreads();

    if (total <= CAP) {
        // stage runs: 4-lane group per chunk, PURE COPY
        const int g = t >> 2;
        const int sl = t & 3;
        for (int ch = g; ch < nch; ch += 64) {
            const int c = scnt16[ch];
            const int cbase = (ch << ch_bits) + soff16[ch];
            const int dst = sst16[ch];
            for (int k = sl; k < c; k += 4)
                buf[dst + k] = pairs[cbase + k];
        }
        __syncthreads();
        const unsigned* bufx = (const unsigned*)buf;
        for (int i = t; i < total; i += 256)
            atomicAdd(&hist[1 + (int)(bufx[2 * i] >> COL_BITS)], 1);
        __syncthreads();
        if (w == 0) {
            int v = hist[1 + lane];
            for (int d = 1; d < 64; d <<= 1) {
                int n = __shfl_up(v, d);
                if (lane >= d) v += n;
            }
            hist[1 + lane] = v;
        }
        __syncthreads();
        if (w == 0) lcur[lane] = hist[lane];
        __syncthreads();
        for (int i = t; i < total; i += 256) {
            int rl = (int)(bufx[2 * i] >> COL_BITS);
            int pos = atomicAdd(&lcur[rl], 1);
            srt16[pos] = (unsigned short)i;
        }
        __syncthreads();

        // dual-edge reduce: stream S = w*2 + (lane>>5); lane covers 2 features
        const int S = w * 2 + (lane >> 5);      // 0..7
        const int hl = lane & 31;
        const __half* xb = x + 2 * hl;
        #define GH(P, A) do { \
            const int _c = (int)((P).x & COL_MASK); \
            const float _e = __uint_as_float((P).y); \
            const float2 _f = __half22float2(*(const __half2*)(xb + _c * D_FEAT)); \
            A.x += _e * _f.x; A.y += _e * _f.y; } while (0)
        for (int m = 0; m < 8; m += 2) {
            const int rA = S + 8 * m;           // stream's row m
            const int rB = rA + 8;              // stream's row m+1
            int jA = hist[rA], eA = hist[rA + 1];
            int jB = hist[rB], eB = hist[rB + 1];
            float2 aA0 = {0.f, 0.f}, aA1 = {0.f, 0.f};
            float2 aB0 = {0.f, 0.f}, aB1 = {0.f, 0.f};
            while (jA + 4 <= eA && jB + 4 <= eB) {   // divergent per half: ok
                uint2 qa0 = buf[srt16[jA]], qa1 = buf[srt16[jA + 1]];
                uint2 qa2 = buf[srt16[jA + 2]], qa3 = buf[srt16[jA + 3]];
                uint2 qb0 = buf[srt16[jB]], qb1 = buf[srt16[jB + 1]];
                uint2 qb2 = buf[srt16[jB + 2]], qb3 = buf[srt16[jB + 3]];
                GH(qa0, aA0); GH(qa1, aA1); GH(qa2, aA0); GH(qa3, aA1);
                GH(qb0, aB0); GH(qb1, aB1); GH(qb2, aB0); GH(qb3, aB1);
                jA += 4; jB += 4;
            }
            while (jA + 2 <= eA) {
                uint2 q0 = buf[srt16[jA]], q1 = buf[srt16[jA + 1]];
                GH(q0, aA0); GH(q1, aA1); jA += 2;
            }
            while (jB + 2 <= eB) {
                uint2 q0 = buf[srt16[jB]], q1 = buf[srt16[jB + 1]];
                GH(q0, aB0); GH(q1, aB1); jB += 2;
            }
            if (jA < eA) { uint2 q0 = buf[srt16[jA]]; GH(q0, aA0); }
            if (jB < eB) { uint2 q0 = buf[srt16[jB]]; GH(q0, aB0); }
            const int rowA = b * RPB + rA;
            const int rowB = b * RPB + rB;
            if (rowA < n_rows) {
                float2 v; v.x = aA0.x + aA1.x; v.y = aA0.y + aA1.y;
                *(float2*)(out + rowA * D_FEAT + 2 * hl) = v;
            }
            if (rowB < n_rows) {
                float2 v; v.x = aB0.x + aB1.x; v.y = aB0.y + aB1.y;
                *(float2*)(out + rowB * D_FEAT + 2 * hl) = v;
            }
        }
        #undef GH
    } else {
        // overflow bucket (statistically never at mean 800, cap 1152)
        for (int r = w; r < RPB; r += 4) {
            const int row = b * RPB + r;
            if (row < n_rows) out[row * D_FEAT + lane] = 0.0f;
        }
        __syncthreads();
        for (int ch = w; ch < nch; ch += 4) {
            const int cbase = (ch << ch_bits) + soff16[ch];
            const int c = scnt16[ch];
            for (int k = 0; k < c; ++k) {
                const uint2 p = pairs[cbase + k];
                const int rl = (int)(p.x >> COL_BITS);
                const int cc = (int)(p.x & COL_MASK);
                const float m = __uint_as_float(p.y) *
                                __half2float(x[cc * D_FEAT + lane]);
                const int row = b * RPB + rl;
                if (row < n_rows) atomicAdd(&out[row * D_FEAT + lane], m);
            }
        }
    }
}

extern "C" void kernel_launch(void* const* d_in, const int* in_sizes, int n_in,
                              void* d_out, int out_size, void* d_ws, size_t ws_size,
                              hipStream_t stream) {
    const float* x    = (const float*)d_in[1];
    const int*   rows = (const int*)d_in[2];
    const int*   cols = (const int*)d_in[3];
    const float* ev   = (const float*)d_in[4];
    float* out = (float*)d_out;
    const int n_edges = in_sizes[3];
    const int n_rows  = out_size / D_FEAT;
    const int n_x     = in_sizes[1];
    const int n_cols  = n_x / D_FEAT;
    const int nb = (n_rows + RPB - 1) / RPB;

    int ch_bits = 0, nch = 0, use_tt = 0, use_fp16 = 0;
    size_t off_table = 0, off_tableT = 0, off_xh = 0;
    for (int cb = 12; cb <= 13 && ch_bits == 0; ++cb) {
        int nc = (n_edges + (1 << cb) - 1) >> cb;
        size_t pairs_b = ((size_t)nc << cb) * 8;
        size_t tab_b = (size_t)nc * (size_t)(nb + 1) * 2;
        if (nc <= NCH_MAX && ws_size >= pairs_b + tab_b) {
            ch_bits = cb; nch = nc;
            off_table = pairs_b;
            size_t cur = pairs_b + tab_b;
            if (ws_size >= cur + tab_b) {
                use_tt = 1;
                off_tableT = cur;
                cur += tab_b;
            }
            size_t xh_b = (size_t)n_x * 2;
            cur = (cur + 255) & ~(size_t)255;
            if (ws_size >= cur + xh_b && (n_x & 3) == 0) {
                use_fp16 = 1;
                off_xh = cur;
            }
        }
    }

    if (ch_bits == 0 || nb > NB_MAX || n_cols > (1 << COL_BITS) ||
        n_rows > (1 << COL_BITS)) {
        hipMemsetAsync(d_out, 0, (size_t)out_size * sizeof(float), stream);
        spmv_coo_kernel<<<4096, 256, 0, stream>>>(x, rows, cols, ev, out, n_edges);
        return;
    }

    uint2* pairs = (uint2*)d_ws;
    unsigned short* table  = (unsigned short*)((char*)d_ws + off_table);
    unsigned short* tableT = (unsigned short*)((char*)d_ws + off_tableT);
    __half* xh = (__half*)((char*)d_ws + off_xh);

    if (use_fp16)
        convert_x_kernel<<<1024, 256, 0, stream>>>((const float4*)x, xh, n_x / 4);

    chunk_sort_kernel<<<nch, 256, 0, stream>>>(rows, cols, ev, pairs, table,
                                               n_edges, nb, ch_bits);
    if (use_tt) {
        dim3 tg((nch + TT - 1) / TT, (nb + 1 + TT - 1) / TT);
        transpose_table_kernel<<<tg, 256, 0, stream>>>(table, tableT, nch, nb + 1);
    }
    if (use_fp16)
        sort_reduce_h2_kernel<<<nb, 256, 0, stream>>>(
            xh, pairs, table, tableT, out, n_rows, nb, nch, ch_bits, use_tt);
    else
        sort_reduce_f32_kernel<<<nb, 256, 0, stream>>>(
            x, pairs, table, tableT, out, n_rows, nb, nch, ch_bits, use_tt);
}

// Round 15
// 79.136 us; speedup vs baseline: 1.2017x; 1.0347x over previous
//
#include <hip/hip_runtime.h>
#include <hip/hip_fp16.h>

// out = A @ x, A sparse COO (rows, cols, edge_vals), x [N,64] f32.
//
// Pipeline:
//   0. convert_x: x f32 -> fp16 workspace copy (absmax 0.0625 << 0.285 thr).
//   1. chunk_sort: one block per 4096-edge chunk, bucket-sorts into its
//      private pairs[] region (full-line writes), emits u16 offset table.
//   2. transpose_table: [ch][b] -> [b][ch] for contiguous descriptor reads.
//   3. sort_reduce_h4: one block per 64-row bucket. Staging/hist/scan/u16
//      sort as before; reduce processes FOUR EDGES PER LOAD INSTRUCTION:
//      quarter-wave q (16 lanes) owns row-stream S=w*4+q, each lane covers
//      4 features via half4 (one x-row = 128B = 16 lanes x 8B). Round 13->14
//      proved memory INSTRUCTIONS per edge are the currency (2/instr: 59->45us);
//      this doubles to 4/instr.
//
// Hard-won rules: inner loops accumulate in REGISTERS; never make an LDS
// atomic data-dependent on a global load in a hot loop (round 6 = 550us);
// staging must be wide/parallel (round 8 = 109us); global scatter writes
// must be block-private regions (rounds 3-5: WRITE = E*64B); occupancy via
// bucket-split is a wash (round 11); bytes are not the constraint (round 12).

#define D_FEAT   64
#define RPB      64             // rows per bucket
#define RPB_BITS 6
#define COL_BITS 17             // col < 2^17; row-in-bucket in bits [17,23)
#define COL_MASK ((1u << COL_BITS) - 1)
#define CAP      1152           // LDS pair cap per bucket (mean 800, +12 sigma)
#define NB_MAX   1600           // max buckets (1563 used)
#define NCH_MAX  400            // max chunks (306 used at 4096)

// ---------------- fallback (round-1 kernel) ----------------
__global__ void spmv_coo_kernel(const float* __restrict__ x,
                                const int* __restrict__ rows,
                                const int* __restrict__ cols,
                                const float* __restrict__ ev,
                                float* __restrict__ out,
                                int n_edges) {
    const int lane = threadIdx.x & 63;
    const int wave_global = blockIdx.x * (blockDim.x >> 6) + (threadIdx.x >> 6);
    const int n_waves = gridDim.x * (blockDim.x >> 6);
    for (int e = wave_global; e < n_edges; e += n_waves) {
        atomicAdd(&out[rows[e] * D_FEAT + lane], ev[e] * x[cols[e] * D_FEAT + lane]);
    }
}

// ---------------- phase 0: x f32 -> fp16 ----------------
__global__ void __launch_bounds__(256) convert_x_kernel(
        const float4* __restrict__ x4, __half* __restrict__ xh, int n4) {
    int gid = blockIdx.x * blockDim.x + threadIdx.x;
    int stride = gridDim.x * blockDim.x;
    for (int i = gid; i < n4; i += stride) {
        float4 v = x4[i];
        __half2 h0 = __floats2half2_rn(v.x, v.y);
        __half2 h1 = __floats2half2_rn(v.z, v.w);
        ((__half2*)xh)[2 * i]     = h0;
        ((__half2*)xh)[2 * i + 1] = h1;
    }
}

// ------------- phase 1: per-chunk bucket sort (one block per chunk) --------
__global__ void __launch_bounds__(256) chunk_sort_kernel(
        const int* __restrict__ rows, const int* __restrict__ cols,
        const float* __restrict__ ev,
        uint2* __restrict__ pairs, unsigned short* __restrict__ table,
        int n_edges, int nb, int ch_bits) {
    __shared__ int sh_cnt[NB_MAX];
    __shared__ int sh_off[NB_MAX];
    __shared__ int sb[256];
    const int t = threadIdx.x;
    const int ch = blockIdx.x;
    const int base = ch << ch_bits;
    const int cnt = min(1 << ch_bits, n_edges - base);

    for (int i = t; i < nb; i += 256) sh_cnt[i] = 0;
    __syncthreads();
    for (int i = t; i < cnt; i += 256)
        atomicAdd(&sh_cnt[rows[base + i] >> RPB_BITS], 1);
    __syncthreads();

    const int items = (nb + 255) / 256;
    const int i0 = t * items;
    int s = 0;
    for (int j = 0; j < items; ++j) {
        int idx = i0 + j;
        if (idx < nb) s += sh_cnt[idx];
    }
    sb[t] = s;
    __syncthreads();
    for (int off = 1; off < 256; off <<= 1) {
        int tmp = (t >= off) ? sb[t - off] : 0;
        __syncthreads();
        sb[t] += tmp;
        __syncthreads();
    }
    int run = sb[t] - s;
    for (int j = 0; j < items; ++j) {
        int idx = i0 + j;
        if (idx < nb) { sh_off[idx] = run; run += sh_cnt[idx]; }
    }
    __syncthreads();

    unsigned short* trow = table + (size_t)ch * (nb + 1);
    for (int i = t; i < nb; i += 256) trow[i] = (unsigned short)sh_off[i];
    if (t == 0) trow[nb] = (unsigned short)cnt;
    __syncthreads();

    for (int i = t; i < cnt; i += 256) {
        int r = rows[base + i];
        int bk = r >> RPB_BITS;
        int pos = atomicAdd(&sh_off[bk], 1);
        uint2 p;
        p.x = (unsigned)cols[base + i] | ((unsigned)(r & (RPB - 1)) << COL_BITS);
        p.y = __float_as_uint(ev[base + i]);
        pairs[base + pos] = p;
    }
}

// ------------- phase 2: table transpose [ch][b] -> [b][ch] -----------------
#define TT 64
__global__ void __launch_bounds__(256) transpose_table_kernel(
        const unsigned short* __restrict__ table,
        unsigned short* __restrict__ tableT,
        int nch, int ncols /* nb+1 */) {
    __shared__ unsigned short tile[TT][TT + 1];
    const int r0 = blockIdx.x * TT;
    const int c0 = blockIdx.y * TT;
    for (int idx = threadIdx.x; idx < TT * TT; idx += 256) {
        int r = idx >> 6, c = idx & 63;
        int ch = r0 + r, b = c0 + c;
        tile[r][c] = (ch < nch && b < ncols) ? table[(size_t)ch * ncols + b] : 0;
    }
    __syncthreads();
    for (int idx = threadIdx.x; idx < TT * TT; idx += 256) {
        int b = idx >> 6, c = idx & 63;
        int gb = c0 + b, gch = r0 + c;
        if (gb < ncols && gch < nch)
            tableT[(size_t)gb * nch + gch] = tile[c][b];
    }
}

// ------------- phase 3a: f32 fallback reduce (round-12 structure) ----------
__global__ void __launch_bounds__(256) sort_reduce_f32_kernel(
        const float* __restrict__ x,
        const uint2* __restrict__ pairs,
        const unsigned short* __restrict__ table,
        const unsigned short* __restrict__ tableT,
        float* __restrict__ out,
        int n_rows, int nb, int nch, int ch_bits, int use_tt) {
    __shared__ uint2 buf[CAP];
    __shared__ unsigned short srt16[CAP];
    __shared__ unsigned short scnt16[NCH_MAX];
    __shared__ unsigned short soff16[NCH_MAX];
    __shared__ unsigned short sst16[NCH_MAX];
    __shared__ int sb[256];
    __shared__ int hist[RPB + 1];
    __shared__ int lcur[RPB];
    const int t = threadIdx.x;
    const int lane = t & 63;
    const int w = t >> 6;
    const int b = blockIdx.x;

    const int items = (nch + 255) / 256;
    const int c0 = t * items;
    int s = 0;
    if (use_tt) {
        const unsigned short* rowB0 = tableT + (size_t)b * nch;
        const unsigned short* rowB1 = tableT + (size_t)(b + 1) * nch;
        for (int j = 0; j < items; ++j) {
            int ch = c0 + j;
            if (ch < nch) {
                int o1 = rowB0[ch], o2 = rowB1[ch];
                scnt16[ch] = (unsigned short)(o2 - o1);
                soff16[ch] = (unsigned short)o1;
                s += o2 - o1;
            }
        }
    } else {
        for (int j = 0; j < items; ++j) {
            int ch = c0 + j;
            if (ch < nch) {
                const unsigned short* trow = table + (size_t)ch * (nb + 1) + b;
                int o1 = trow[0], o2 = trow[1];
                scnt16[ch] = (unsigned short)(o2 - o1);
                soff16[ch] = (unsigned short)o1;
                s += o2 - o1;
            }
        }
    }
    sb[t] = s;
    __syncthreads();
    for (int off = 1; off < 256; off <<= 1) {
        int tmp = (t >= off) ? sb[t - off] : 0;
        __syncthreads();
        sb[t] += tmp;
        __syncthreads();
    }
    const int total = sb[255];
    int run = sb[t] - s;
    for (int j = 0; j < items; ++j) {
        int ch = c0 + j;
        if (ch < nch) { sst16[ch] = (unsigned short)run; run += scnt16[ch]; }
    }
    if (t <= RPB) hist[t] = 0;
    __syncthreads();

    if (total <= CAP) {
        const int g = t >> 2;
        const int sl = t & 3;
        for (int ch = g; ch < nch; ch += 64) {
            const int c = scnt16[ch];
            const int cbase = (ch << ch_bits) + soff16[ch];
            const int dst = sst16[ch];
            for (int k = sl; k < c; k += 4)
                buf[dst + k] = pairs[cbase + k];
        }
        __syncthreads();
        const unsigned* bufx = (const unsigned*)buf;
        for (int i = t; i < total; i += 256)
            atomicAdd(&hist[1 + (int)(bufx[2 * i] >> COL_BITS)], 1);
        __syncthreads();
        if (w == 0) {
            int v = hist[1 + lane];
            for (int d = 1; d < 64; d <<= 1) {
                int n = __shfl_up(v, d);
                if (lane >= d) v += n;
            }
            hist[1 + lane] = v;
        }
        __syncthreads();
        if (w == 0) lcur[lane] = hist[lane];
        __syncthreads();
        for (int i = t; i < total; i += 256) {
            int rl = (int)(bufx[2 * i] >> COL_BITS);
            int pos = atomicAdd(&lcur[rl], 1);
            srt16[pos] = (unsigned short)i;
        }
        __syncthreads();
        const float* xl = x + lane;
        for (int q = 0; q < RPB / 8; ++q) {
            const int rA = w + 8 * q;
            const int rB = rA + 4;
            int jA = hist[rA], eA = hist[rA + 1];
            int jB = hist[rB], eB = hist[rB + 1];
            float aA0 = 0.f, aA1 = 0.f, aB0 = 0.f, aB1 = 0.f;
            #define GF(P) (__uint_as_float((P).y) * xl[(int)((P).x & COL_MASK) * D_FEAT])
            while (jA + 4 <= eA && jB + 4 <= eB) {
                uint2 pa0 = buf[srt16[jA]], pa1 = buf[srt16[jA + 1]];
                uint2 pa2 = buf[srt16[jA + 2]], pa3 = buf[srt16[jA + 3]];
                uint2 pb0 = buf[srt16[jB]], pb1 = buf[srt16[jB + 1]];
                uint2 pb2 = buf[srt16[jB + 2]], pb3 = buf[srt16[jB + 3]];
                aA0 += GF(pa0); aA1 += GF(pa1); aA0 += GF(pa2); aA1 += GF(pa3);
                aB0 += GF(pb0); aB1 += GF(pb1); aB0 += GF(pb2); aB1 += GF(pb3);
                jA += 4; jB += 4;
            }
            while (jA + 2 <= eA) {
                uint2 p0 = buf[srt16[jA]], p1 = buf[srt16[jA + 1]];
                aA0 += GF(p0); aA1 += GF(p1); jA += 2;
            }
            while (jB + 2 <= eB) {
                uint2 p0 = buf[srt16[jB]], p1 = buf[srt16[jB + 1]];
                aB0 += GF(p0); aB1 += GF(p1); jB += 2;
            }
            if (jA < eA) { uint2 p0 = buf[srt16[jA]]; aA0 += GF(p0); }
            if (jB < eB) { uint2 p0 = buf[srt16[jB]]; aB0 += GF(p0); }
            #undef GF
            const int rowA = b * RPB + rA;
            const int rowB = b * RPB + rB;
            if (rowA < n_rows) out[rowA * D_FEAT + lane] = aA0 + aA1;
            if (rowB < n_rows) out[rowB * D_FEAT + lane] = aB0 + aB1;
        }
    } else {
        for (int r = w; r < RPB; r += 4) {
            const int row = b * RPB + r;
            if (row < n_rows) out[row * D_FEAT + lane] = 0.0f;
        }
        __syncthreads();
        for (int ch = w; ch < nch; ch += 4) {
            const int cbase = (ch << ch_bits) + soff16[ch];
            const int c = scnt16[ch];
            for (int k = 0; k < c; ++k) {
                const uint2 p = pairs[cbase + k];
                const int rl = (int)(p.x >> COL_BITS);
                const int cc = (int)(p.x & COL_MASK);
                const float m = __uint_as_float(p.y) * x[cc * D_FEAT + lane];
                const int row = b * RPB + rl;
                if (row < n_rows) atomicAdd(&out[row * D_FEAT + lane], m);
            }
        }
    }
}

// ------------- phase 3b: fp16 half4 QUAD-EDGE reduce -----------------------
// Quarter-wave q (lanes q*16..q*16+15) owns row-stream S = w*4+q; each lane
// covers features {4*ql..4*ql+3} via half4 (one x-row = 128B = 16 lanes x 8B).
// One load instruction gathers FOUR x-rows -> VMEM+LDS instr/edge halved
// again vs round 14's h2 (59 -> 45us).
__global__ void __launch_bounds__(256) sort_reduce_h4_kernel(
        const __half* __restrict__ x,
        const uint2* __restrict__ pairs,
        const unsigned short* __restrict__ table,
        const unsigned short* __restrict__ tableT,
        float* __restrict__ out,
        int n_rows, int nb, int nch, int ch_bits, int use_tt) {
    __shared__ uint2 buf[CAP];
    __shared__ unsigned short srt16[CAP];
    __shared__ unsigned short scnt16[NCH_MAX];
    __shared__ unsigned short soff16[NCH_MAX];
    __shared__ unsigned short sst16[NCH_MAX];
    __shared__ int sb[256];
    __shared__ int hist[RPB + 1];
    __shared__ int lcur[RPB];
    const int t = threadIdx.x;
    const int lane = t & 63;
    const int w = t >> 6;
    const int b = blockIdx.x;

    const int items = (nch + 255) / 256;
    const int c0 = t * items;
    int s = 0;
    if (use_tt) {
        const unsigned short* rowB0 = tableT + (size_t)b * nch;
        const unsigned short* rowB1 = tableT + (size_t)(b + 1) * nch;
        for (int j = 0; j < items; ++j) {
            int ch = c0 + j;
            if (ch < nch) {
                int o1 = rowB0[ch], o2 = rowB1[ch];
                scnt16[ch] = (unsigned short)(o2 - o1);
                soff16[ch] = (unsigned short)o1;
                s += o2 - o1;
            }
        }
    } else {
        for (int j = 0; j < items; ++j) {
            int ch = c0 + j;
            if (ch < nch) {
                const unsigned short* trow = table + (size_t)ch * (nb + 1) + b;
                int o1 = trow[0], o2 = trow[1];
                scnt16[ch] = (unsigned short)(o2 - o1);
                soff16[ch] = (unsigned short)o1;
                s += o2 - o1;
            }
        }
    }
    sb[t] = s;
    __syncthreads();
    for (int off = 1; off < 256; off <<= 1) {
        int tmp = (t >= off) ? sb[t - off] : 0;
        __syncthreads();
        sb[t] += tmp;
        __syncthreads();
    }
    const int total = sb[255];
    int run = sb[t] - s;
    for (int j = 0; j < items; ++j) {
        int ch = c0 + j;
        if (ch < nch) { sst16[ch] = (unsigned short)run; run += scnt16[ch]; }
    }
    if (t <= RPB) hist[t] = 0;
    __syncthreads();

    if (total <= CAP) {
        // stage runs: 4-lane group per chunk, PURE COPY
        const int g = t >> 2;
        const int sl = t & 3;
        for (int ch = g; ch < nch; ch += 64) {
            const int c = scnt16[ch];
            const int cbase = (ch << ch_bits) + soff16[ch];
            const int dst = sst16[ch];
            for (int k = sl; k < c; k += 4)
                buf[dst + k] = pairs[cbase + k];
        }
        __syncthreads();
        const unsigned* bufx = (const unsigned*)buf;
        for (int i = t; i < total; i += 256)
            atomicAdd(&hist[1 + (int)(bufx[2 * i] >> COL_BITS)], 1);
        __syncthreads();
        if (w == 0) {
            int v = hist[1 + lane];
            for (int d = 1; d < 64; d <<= 1) {
                int n = __shfl_up(v, d);
                if (lane >= d) v += n;
            }
            hist[1 + lane] = v;
        }
        __syncthreads();
        if (w == 0) lcur[lane] = hist[lane];
        __syncthreads();
        for (int i = t; i < total; i += 256) {
            int rl = (int)(bufx[2 * i] >> COL_BITS);
            int pos = atomicAdd(&lcur[rl], 1);
            srt16[pos] = (unsigned short)i;
        }
        __syncthreads();

        // quad-edge reduce: stream S = w*4 + (lane>>4); lane covers 4 features
        const int S = w * 4 + (lane >> 4);      // 0..15
        const int ql = lane & 15;
        const __half* xb = x + 4 * ql;
        #define GH4(P, A) do { \
            const int _c = (int)((P).x & COL_MASK); \
            const float _e = __uint_as_float((P).y); \
            const float2 _raw = *(const float2*)(xb + _c * D_FEAT); \
            const float2 _f01 = __half22float2(*(const __half2*)&_raw.x); \
            const float2 _f23 = __half22float2(*(const __half2*)&_raw.y); \
            A.x += _e * _f01.x; A.y += _e * _f01.y; \
            A.z += _e * _f23.x; A.w += _e * _f23.y; } while (0)
        for (int m = 0; m < 4; m += 2) {
            const int rA = S + 16 * m;          // stream's row m
            const int rB = rA + 16;             // stream's row m+1
            int jA = hist[rA], eA = hist[rA + 1];
            int jB = hist[rB], eB = hist[rB + 1];
            float4 aA0 = {0.f, 0.f, 0.f, 0.f}, aA1 = {0.f, 0.f, 0.f, 0.f};
            float4 aB0 = {0.f, 0.f, 0.f, 0.f}, aB1 = {0.f, 0.f, 0.f, 0.f};
            while (jA + 4 <= eA && jB + 4 <= eB) {   // divergent per quarter: ok
                uint2 qa0 = buf[srt16[jA]], qa1 = buf[srt16[jA + 1]];
                uint2 qa2 = buf[srt16[jA + 2]], qa3 = buf[srt16[jA + 3]];
                uint2 qb0 = buf[srt16[jB]], qb1 = buf[srt16[jB + 1]];
                uint2 qb2 = buf[srt16[jB + 2]], qb3 = buf[srt16[jB + 3]];
                GH4(qa0, aA0); GH4(qa1, aA1); GH4(qa2, aA0); GH4(qa3, aA1);
                GH4(qb0, aB0); GH4(qb1, aB1); GH4(qb2, aB0); GH4(qb3, aB1);
                jA += 4; jB += 4;
            }
            while (jA + 2 <= eA) {
                uint2 q0 = buf[srt16[jA]], q1 = buf[srt16[jA + 1]];
                GH4(q0, aA0); GH4(q1, aA1); jA += 2;
            }
            while (jB + 2 <= eB) {
                uint2 q0 = buf[srt16[jB]], q1 = buf[srt16[jB + 1]];
                GH4(q0, aB0); GH4(q1, aB1); jB += 2;
            }
            if (jA < eA) { uint2 q0 = buf[srt16[jA]]; GH4(q0, aA0); }
            if (jB < eB) { uint2 q0 = buf[srt16[jB]]; GH4(q0, aB0); }
            const int rowA = b * RPB + rA;
            const int rowB = b * RPB + rB;
            if (rowA < n_rows) {
                float4 v;
                v.x = aA0.x + aA1.x; v.y = aA0.y + aA1.y;
                v.z = aA0.z + aA1.z; v.w = aA0.w + aA1.w;
                *(float4*)(out + rowA * D_FEAT + 4 * ql) = v;
            }
            if (rowB < n_rows) {
                float4 v;
                v.x = aB0.x + aB1.x; v.y = aB0.y + aB1.y;
                v.z = aB0.z + aB1.z; v.w = aB0.w + aB1.w;
                *(float4*)(out + rowB * D_FEAT + 4 * ql) = v;
            }
        }
        #undef GH4
    } else {
        // overflow bucket (statistically never at mean 800, cap 1152)
        for (int r = w; r < RPB; r += 4) {
            const int row = b * RPB + r;
            if (row < n_rows) out[row * D_FEAT + lane] = 0.0f;
        }
        __syncthreads();
        for (int ch = w; ch < nch; ch += 4) {
            const int cbase = (ch << ch_bits) + soff16[ch];
            const int c = scnt16[ch];
            for (int k = 0; k < c; ++k) {
                const uint2 p = pairs[cbase + k];
                const int rl = (int)(p.x >> COL_BITS);
                const int cc = (int)(p.x & COL_MASK);
                const float m = __uint_as_float(p.y) *
                                __half2float(x[cc * D_FEAT + lane]);
                const int row = b * RPB + rl;
                if (row < n_rows) atomicAdd(&out[row * D_FEAT + lane], m);
            }
        }
    }
}

extern "C" void kernel_launch(void* const* d_in, const int* in_sizes, int n_in,
                              void* d_out, int out_size, void* d_ws, size_t ws_size,
                              hipStream_t stream) {
    const float* x    = (const float*)d_in[1];
    const int*   rows = (const int*)d_in[2];
    const int*   cols = (const int*)d_in[3];
    const float* ev   = (const float*)d_in[4];
    float* out = (float*)d_out;
    const int n_edges = in_sizes[3];
    const int n_rows  = out_size / D_FEAT;
    const int n_x     = in_sizes[1];
    const int n_cols  = n_x / D_FEAT;
    const int nb = (n_rows + RPB - 1) / RPB;

    int ch_bits = 0, nch = 0, use_tt = 0, use_fp16 = 0;
    size_t off_table = 0, off_tableT = 0, off_xh = 0;
    for (int cb = 12; cb <= 13 && ch_bits == 0; ++cb) {
        int nc = (n_edges + (1 << cb) - 1) >> cb;
        size_t pairs_b = ((size_t)nc << cb) * 8;
        size_t tab_b = (size_t)nc * (size_t)(nb + 1) * 2;
        if (nc <= NCH_MAX && ws_size >= pairs_b + tab_b) {
            ch_bits = cb; nch = nc;
            off_table = pairs_b;
            size_t cur = pairs_b + tab_b;
            if (ws_size >= cur + tab_b) {
                use_tt = 1;
                off_tableT = cur;
                cur += tab_b;
            }
            size_t xh_b = (size_t)n_x * 2;
            cur = (cur + 255) & ~(size_t)255;
            if (ws_size >= cur + xh_b && (n_x & 3) == 0) {
                use_fp16 = 1;
                off_xh = cur;
            }
        }
    }

    if (ch_bits == 0 || nb > NB_MAX || n_cols > (1 << COL_BITS) ||
        n_rows > (1 << COL_BITS)) {
        hipMemsetAsync(d_out, 0, (size_t)out_size * sizeof(float), stream);
        spmv_coo_kernel<<<4096, 256, 0, stream>>>(x, rows, cols, ev, out, n_edges);
        return;
    }

    uint2* pairs = (uint2*)d_ws;
    unsigned short* table  = (unsigned short*)((char*)d_ws + off_table);
    unsigned short* tableT = (unsigned short*)((char*)d_ws + off_tableT);
    __half* xh = (__half*)((char*)d_ws + off_xh);

    if (use_fp16)
        convert_x_kernel<<<1024, 256, 0, stream>>>((const float4*)x, xh, n_x / 4);

    chunk_sort_kernel<<<nch, 256, 0, stream>>>(rows, cols, ev, pairs, table,
                                               n_edges, nb, ch_bits);
    if (use_tt) {
        dim3 tg((nch + TT - 1) / TT, (nb + 1 + TT - 1) / TT);
        transpose_table_kernel<<<tg, 256, 0, stream>>>(table, tableT, nch, nb + 1);
    }
    if (use_fp16)
        sort_reduce_h4_kernel<<<nb, 256, 0, stream>>>(
            xh, pairs, table, tableT, out, n_rows, nb, nch, ch_bits, use_tt);
    else
        sort_reduce_f32_kernel<<<nb, 256, 0, stream>>>(
            x, pairs, table, tableT, out, n_rows, nb, nch, ch_bits, use_tt);
}

// Round 16
// 71.982 us; speedup vs baseline: 1.3212x; 1.0994x over previous
//
#include <hip/hip_runtime.h>
#include <hip/hip_fp16.h>

// out = A @ x, A sparse COO (rows, cols, edge_vals), x [N,64] f32.
//
// Pipeline:
//   1. chunk_sort (1024 thr, fused x->fp16 convert prologue): one block per
//      4096-edge chunk, bucket-sorts into its private pairs[] region
//      (full-line writes), emits u16 offset table. 1024 threads because 306
//      blocks = 1.2/CU was latency-starved at 256 thr (~22us for ~5us of
//      traffic); the grid-stride convert loop hides in the same stalls.
//   2. transpose_table: [ch][b] -> [b][ch] for contiguous descriptor reads.
//   3. sort_reduce_h4 (round-15, proven): one block per 64-row bucket;
//      parallel pure-copy staging -> LDS hist -> shfl scan -> u16 index sort
//      -> QUAD-EDGE reduce (quarter-wave owns a row-stream, lane covers 4
//      features via half4; 4 edges per VMEM instruction). Rounds 13-15
//      proved memory INSTRUCTIONS per edge are the currency (59->45->41.7us
//      for 1->2->4 edges/instr).
//
// Hard-won rules: inner loops accumulate in REGISTERS; never make an LDS
// atomic data-dependent on a global load in a hot loop (round 6 = 550us);
// staging must be wide/parallel (round 8 = 109us); global scatter writes
// must be block-private regions (rounds 3-5: WRITE = E*64B); occupancy via
// bucket-split is a wash (round 11); bytes are not the constraint (round 12).

#define D_FEAT   64
#define RPB      64             // rows per bucket
#define RPB_BITS 6
#define COL_BITS 17             // col < 2^17; row-in-bucket in bits [17,23)
#define COL_MASK ((1u << COL_BITS) - 1)
#define CAP      1152           // LDS pair cap per bucket (mean 800, +12 sigma)
#define NB_MAX   1600           // max buckets (1563 used)
#define NCH_MAX  400            // max chunks (306 used at 4096)

// ---------------- fallback (round-1 kernel) ----------------
__global__ void spmv_coo_kernel(const float* __restrict__ x,
                                const int* __restrict__ rows,
                                const int* __restrict__ cols,
                                const float* __restrict__ ev,
                                float* __restrict__ out,
                                int n_edges) {
    const int lane = threadIdx.x & 63;
    const int wave_global = blockIdx.x * (blockDim.x >> 6) + (threadIdx.x >> 6);
    const int n_waves = gridDim.x * (blockDim.x >> 6);
    for (int e = wave_global; e < n_edges; e += n_waves) {
        atomicAdd(&out[rows[e] * D_FEAT + lane], ev[e] * x[cols[e] * D_FEAT + lane]);
    }
}

// ------- phase 1: fused convert + per-chunk bucket sort (1024 thr) ---------
__global__ void __launch_bounds__(1024) chunk_sort_kernel(
        const int* __restrict__ rows, const int* __restrict__ cols,
        const float* __restrict__ ev,
        uint2* __restrict__ pairs, unsigned short* __restrict__ table,
        const float4* __restrict__ x4, __half* __restrict__ xh, int n4,
        int n_edges, int nb, int ch_bits) {
    __shared__ int sh_cnt[NB_MAX];
    __shared__ int sh_off[NB_MAX];
    __shared__ int sb[1024];
    const int t = threadIdx.x;
    const int ch = blockIdx.x;
    const int base = ch << ch_bits;
    const int cnt = min(1 << ch_bits, n_edges - base);

    // fused x f32 -> fp16 convert (grid-stride; hides in sort's stalls)
    if (xh) {
        int gid = ch * 1024 + t;
        int stride = gridDim.x * 1024;
        for (int i = gid; i < n4; i += stride) {
            float4 v = x4[i];
            __half2 h0 = __floats2half2_rn(v.x, v.y);
            __half2 h1 = __floats2half2_rn(v.z, v.w);
            ((__half2*)xh)[2 * i]     = h0;
            ((__half2*)xh)[2 * i + 1] = h1;
        }
    }

    for (int i = t; i < nb; i += 1024) sh_cnt[i] = 0;
    __syncthreads();
    for (int i = t; i < cnt; i += 1024)
        atomicAdd(&sh_cnt[rows[base + i] >> RPB_BITS], 1);
    __syncthreads();

    // hierarchical exclusive scan over nb bins
    const int items = (nb + 1023) / 1024;
    const int i0 = t * items;
    int s = 0;
    for (int j = 0; j < items; ++j) {
        int idx = i0 + j;
        if (idx < nb) s += sh_cnt[idx];
    }
    sb[t] = s;
    __syncthreads();
    for (int off = 1; off < 1024; off <<= 1) {
        int tmp = (t >= off) ? sb[t - off] : 0;
        __syncthreads();
        sb[t] += tmp;
        __syncthreads();
    }
    int run = sb[t] - s;
    for (int j = 0; j < items; ++j) {
        int idx = i0 + j;
        if (idx < nb) { sh_off[idx] = run; run += sh_cnt[idx]; }
    }
    __syncthreads();

    unsigned short* trow = table + (size_t)ch * (nb + 1);
    for (int i = t; i < nb; i += 1024) trow[i] = (unsigned short)sh_off[i];
    if (t == 0) trow[nb] = (unsigned short)cnt;
    __syncthreads();

    for (int i = t; i < cnt; i += 1024) {
        int r = rows[base + i];
        int bk = r >> RPB_BITS;
        int pos = atomicAdd(&sh_off[bk], 1);
        uint2 p;
        p.x = (unsigned)cols[base + i] | ((unsigned)(r & (RPB - 1)) << COL_BITS);
        p.y = __float_as_uint(ev[base + i]);
        pairs[base + pos] = p;
    }
}

// ------------- phase 2: table transpose [ch][b] -> [b][ch] -----------------
#define TT 64
__global__ void __launch_bounds__(256) transpose_table_kernel(
        const unsigned short* __restrict__ table,
        unsigned short* __restrict__ tableT,
        int nch, int ncols /* nb+1 */) {
    __shared__ unsigned short tile[TT][TT + 1];
    const int r0 = blockIdx.x * TT;
    const int c0 = blockIdx.y * TT;
    for (int idx = threadIdx.x; idx < TT * TT; idx += 256) {
        int r = idx >> 6, c = idx & 63;
        int ch = r0 + r, b = c0 + c;
        tile[r][c] = (ch < nch && b < ncols) ? table[(size_t)ch * ncols + b] : 0;
    }
    __syncthreads();
    for (int idx = threadIdx.x; idx < TT * TT; idx += 256) {
        int b = idx >> 6, c = idx & 63;
        int gb = c0 + b, gch = r0 + c;
        if (gb < ncols && gch < nch)
            tableT[(size_t)gb * nch + gch] = tile[c][b];
    }
}

// ------------- phase 3a: f32 fallback reduce (round-12 structure) ----------
__global__ void __launch_bounds__(256) sort_reduce_f32_kernel(
        const float* __restrict__ x,
        const uint2* __restrict__ pairs,
        const unsigned short* __restrict__ table,
        const unsigned short* __restrict__ tableT,
        float* __restrict__ out,
        int n_rows, int nb, int nch, int ch_bits, int use_tt) {
    __shared__ uint2 buf[CAP];
    __shared__ unsigned short srt16[CAP];
    __shared__ unsigned short scnt16[NCH_MAX];
    __shared__ unsigned short soff16[NCH_MAX];
    __shared__ unsigned short sst16[NCH_MAX];
    __shared__ int sb[256];
    __shared__ int hist[RPB + 1];
    __shared__ int lcur[RPB];
    const int t = threadIdx.x;
    const int lane = t & 63;
    const int w = t >> 6;
    const int b = blockIdx.x;

    const int items = (nch + 255) / 256;
    const int c0 = t * items;
    int s = 0;
    if (use_tt) {
        const unsigned short* rowB0 = tableT + (size_t)b * nch;
        const unsigned short* rowB1 = tableT + (size_t)(b + 1) * nch;
        for (int j = 0; j < items; ++j) {
            int ch = c0 + j;
            if (ch < nch) {
                int o1 = rowB0[ch], o2 = rowB1[ch];
                scnt16[ch] = (unsigned short)(o2 - o1);
                soff16[ch] = (unsigned short)o1;
                s += o2 - o1;
            }
        }
    } else {
        for (int j = 0; j < items; ++j) {
            int ch = c0 + j;
            if (ch < nch) {
                const unsigned short* trow = table + (size_t)ch * (nb + 1) + b;
                int o1 = trow[0], o2 = trow[1];
                scnt16[ch] = (unsigned short)(o2 - o1);
                soff16[ch] = (unsigned short)o1;
                s += o2 - o1;
            }
        }
    }
    sb[t] = s;
    __syncthreads();
    for (int off = 1; off < 256; off <<= 1) {
        int tmp = (t >= off) ? sb[t - off] : 0;
        __syncthreads();
        sb[t] += tmp;
        __syncthreads();
    }
    const int total = sb[255];
    int run = sb[t] - s;
    for (int j = 0; j < items; ++j) {
        int ch = c0 + j;
        if (ch < nch) { sst16[ch] = (unsigned short)run; run += scnt16[ch]; }
    }
    if (t <= RPB) hist[t] = 0;
    __syncthreads();

    if (total <= CAP) {
        const int g = t >> 2;
        const int sl = t & 3;
        for (int ch = g; ch < nch; ch += 64) {
            const int c = scnt16[ch];
            const int cbase = (ch << ch_bits) + soff16[ch];
            const int dst = sst16[ch];
            for (int k = sl; k < c; k += 4)
                buf[dst + k] = pairs[cbase + k];
        }
        __syncthreads();
        const unsigned* bufx = (const unsigned*)buf;
        for (int i = t; i < total; i += 256)
            atomicAdd(&hist[1 + (int)(bufx[2 * i] >> COL_BITS)], 1);
        __syncthreads();
        if (w == 0) {
            int v = hist[1 + lane];
            for (int d = 1; d < 64; d <<= 1) {
                int n = __shfl_up(v, d);
                if (lane >= d) v += n;
            }
            hist[1 + lane] = v;
        }
        __syncthreads();
        if (w == 0) lcur[lane] = hist[lane];
        __syncthreads();
        for (int i = t; i < total; i += 256) {
            int rl = (int)(bufx[2 * i] >> COL_BITS);
            int pos = atomicAdd(&lcur[rl], 1);
            srt16[pos] = (unsigned short)i;
        }
        __syncthreads();
        const float* xl = x + lane;
        for (int q = 0; q < RPB / 8; ++q) {
            const int rA = w + 8 * q;
            const int rB = rA + 4;
            int jA = hist[rA], eA = hist[rA + 1];
            int jB = hist[rB], eB = hist[rB + 1];
            float aA0 = 0.f, aA1 = 0.f, aB0 = 0.f, aB1 = 0.f;
            #define GF(P) (__uint_as_float((P).y) * xl[(int)((P).x & COL_MASK) * D_FEAT])
            while (jA + 4 <= eA && jB + 4 <= eB) {
                uint2 pa0 = buf[srt16[jA]], pa1 = buf[srt16[jA + 1]];
                uint2 pa2 = buf[srt16[jA + 2]], pa3 = buf[srt16[jA + 3]];
                uint2 pb0 = buf[srt16[jB]], pb1 = buf[srt16[jB + 1]];
                uint2 pb2 = buf[srt16[jB + 2]], pb3 = buf[srt16[jB + 3]];
                aA0 += GF(pa0); aA1 += GF(pa1); aA0 += GF(pa2); aA1 += GF(pa3);
                aB0 += GF(pb0); aB1 += GF(pb1); aB0 += GF(pb2); aB1 += GF(pb3);
                jA += 4; jB += 4;
            }
            while (jA + 2 <= eA) {
                uint2 p0 = buf[srt16[jA]], p1 = buf[srt16[jA + 1]];
                aA0 += GF(p0); aA1 += GF(p1); jA += 2;
            }
            while (jB + 2 <= eB) {
                uint2 p0 = buf[srt16[jB]], p1 = buf[srt16[jB + 1]];
                aB0 += GF(p0); aB1 += GF(p1); jB += 2;
            }
            if (jA < eA) { uint2 p0 = buf[srt16[jA]]; aA0 += GF(p0); }
            if (jB < eB) { uint2 p0 = buf[srt16[jB]]; aB0 += GF(p0); }
            #undef GF
            const int rowA = b * RPB + rA;
            const int rowB = b * RPB + rB;
            if (rowA < n_rows) out[rowA * D_FEAT + lane] = aA0 + aA1;
            if (rowB < n_rows) out[rowB * D_FEAT + lane] = aB0 + aB1;
        }
    } else {
        for (int r = w; r < RPB; r += 4) {
            const int row = b * RPB + r;
            if (row < n_rows) out[row * D_FEAT + lane] = 0.0f;
        }
        __syncthreads();
        for (int ch = w; ch < nch; ch += 4) {
            const int cbase = (ch << ch_bits) + soff16[ch];
            const int c = scnt16[ch];
            for (int k = 0; k < c; ++k) {
                const uint2 p = pairs[cbase + k];
                const int rl = (int)(p.x >> COL_BITS);
                const int cc = (int)(p.x & COL_MASK);
                const float m = __uint_as_float(p.y) * x[cc * D_FEAT + lane];
                const int row = b * RPB + rl;
                if (row < n_rows) atomicAdd(&out[row * D_FEAT + lane], m);
            }
        }
    }
}

// ------------- phase 3b: fp16 half4 QUAD-EDGE reduce (round-15) ------------
__global__ void __launch_bounds__(256) sort_reduce_h4_kernel(
        const __half* __restrict__ x,
        const uint2* __restrict__ pairs,
        const unsigned short* __restrict__ table,
        const unsigned short* __restrict__ tableT,
        float* __restrict__ out,
        int n_rows, int nb, int nch, int ch_bits, int use_tt) {
    __shared__ uint2 buf[CAP];
    __shared__ unsigned short srt16[CAP];
    __shared__ unsigned short scnt16[NCH_MAX];
    __shared__ unsigned short soff16[NCH_MAX];
    __shared__ unsigned short sst16[NCH_MAX];
    __shared__ int sb[256];
    __shared__ int hist[RPB + 1];
    __shared__ int lcur[RPB];
    const int t = threadIdx.x;
    const int lane = t & 63;
    const int w = t >> 6;
    const int b = blockIdx.x;

    const int items = (nch + 255) / 256;
    const int c0 = t * items;
    int s = 0;
    if (use_tt) {
        const unsigned short* rowB0 = tableT + (size_t)b * nch;
        const unsigned short* rowB1 = tableT + (size_t)(b + 1) * nch;
        for (int j = 0; j < items; ++j) {
            int ch = c0 + j;
            if (ch < nch) {
                int o1 = rowB0[ch], o2 = rowB1[ch];
                scnt16[ch] = (unsigned short)(o2 - o1);
                soff16[ch] = (unsigned short)o1;
                s += o2 - o1;
            }
        }
    } else {
        for (int j = 0; j < items; ++j) {
            int ch = c0 + j;
            if (ch < nch) {
                const unsigned short* trow = table + (size_t)ch * (nb + 1) + b;
                int o1 = trow[0], o2 = trow[1];
                scnt16[ch] = (unsigned short)(o2 - o1);
                soff16[ch] = (unsigned short)o1;
                s += o2 - o1;
            }
        }
    }
    sb[t] = s;
    __syncthreads();
    for (int off = 1; off < 256; off <<= 1) {
        int tmp = (t >= off) ? sb[t - off] : 0;
        __syncthreads();
        sb[t] += tmp;
        __syncthreads();
    }
    const int total = sb[255];
    int run = sb[t] - s;
    for (int j = 0; j < items; ++j) {
        int ch = c0 + j;
        if (ch < nch) { sst16[ch] = (unsigned short)run; run += scnt16[ch]; }
    }
    if (t <= RPB) hist[t] = 0;
    __syncthreads();

    if (total <= CAP) {
        const int g = t >> 2;
        const int sl = t & 3;
        for (int ch = g; ch < nch; ch += 64) {
            const int c = scnt16[ch];
            const int cbase = (ch << ch_bits) + soff16[ch];
            const int dst = sst16[ch];
            for (int k = sl; k < c; k += 4)
                buf[dst + k] = pairs[cbase + k];
        }
        __syncthreads();
        const unsigned* bufx = (const unsigned*)buf;
        for (int i = t; i < total; i += 256)
            atomicAdd(&hist[1 + (int)(bufx[2 * i] >> COL_BITS)], 1);
        __syncthreads();
        if (w == 0) {
            int v = hist[1 + lane];
            for (int d = 1; d < 64; d <<= 1) {
                int n = __shfl_up(v, d);
                if (lane >= d) v += n;
            }
            hist[1 + lane] = v;
        }
        __syncthreads();
        if (w == 0) lcur[lane] = hist[lane];
        __syncthreads();
        for (int i = t; i < total; i += 256) {
            int rl = (int)(bufx[2 * i] >> COL_BITS);
            int pos = atomicAdd(&lcur[rl], 1);
            srt16[pos] = (unsigned short)i;
        }
        __syncthreads();

        // quad-edge reduce: stream S = w*4 + (lane>>4); lane covers 4 features
        const int S = w * 4 + (lane >> 4);      // 0..15
        const int ql = lane & 15;
        const __half* xb = x + 4 * ql;
        #define GH4(P, A) do { \
            const int _c = (int)((P).x & COL_MASK); \
            const float _e = __uint_as_float((P).y); \
            const float2 _raw = *(const float2*)(xb + _c * D_FEAT); \
            const float2 _f01 = __half22float2(*(const __half2*)&_raw.x); \
            const float2 _f23 = __half22float2(*(const __half2*)&_raw.y); \
            A.x += _e * _f01.x; A.y += _e * _f01.y; \
            A.z += _e * _f23.x; A.w += _e * _f23.y; } while (0)
        for (int m = 0; m < 4; m += 2) {
            const int rA = S + 16 * m;
            const int rB = rA + 16;
            int jA = hist[rA], eA = hist[rA + 1];
            int jB = hist[rB], eB = hist[rB + 1];
            float4 aA0 = {0.f, 0.f, 0.f, 0.f}, aA1 = {0.f, 0.f, 0.f, 0.f};
            float4 aB0 = {0.f, 0.f, 0.f, 0.f}, aB1 = {0.f, 0.f, 0.f, 0.f};
            while (jA + 4 <= eA && jB + 4 <= eB) {
                uint2 qa0 = buf[srt16[jA]], qa1 = buf[srt16[jA + 1]];
                uint2 qa2 = buf[srt16[jA + 2]], qa3 = buf[srt16[jA + 3]];
                uint2 qb0 = buf[srt16[jB]], qb1 = buf[srt16[jB + 1]];
                uint2 qb2 = buf[srt16[jB + 2]], qb3 = buf[srt16[jB + 3]];
                GH4(qa0, aA0); GH4(qa1, aA1); GH4(qa2, aA0); GH4(qa3, aA1);
                GH4(qb0, aB0); GH4(qb1, aB1); GH4(qb2, aB0); GH4(qb3, aB1);
                jA += 4; jB += 4;
            }
            while (jA + 2 <= eA) {
                uint2 q0 = buf[srt16[jA]], q1 = buf[srt16[jA + 1]];
                GH4(q0, aA0); GH4(q1, aA1); jA += 2;
            }
            while (jB + 2 <= eB) {
                uint2 q0 = buf[srt16[jB]], q1 = buf[srt16[jB + 1]];
                GH4(q0, aB0); GH4(q1, aB1); jB += 2;
            }
            if (jA < eA) { uint2 q0 = buf[srt16[jA]]; GH4(q0, aA0); }
            if (jB < eB) { uint2 q0 = buf[srt16[jB]]; GH4(q0, aB0); }
            const int rowA = b * RPB + rA;
            const int rowB = b * RPB + rB;
            if (rowA < n_rows) {
                float4 v;
                v.x = aA0.x + aA1.x; v.y = aA0.y + aA1.y;
                v.z = aA0.z + aA1.z; v.w = aA0.w + aA1.w;
                *(float4*)(out + rowA * D_FEAT + 4 * ql) = v;
            }
            if (rowB < n_rows) {
                float4 v;
                v.x = aB0.x + aB1.x; v.y = aB0.y + aB1.y;
                v.z = aB0.z + aB1.z; v.w = aB0.w + aB1.w;
                *(float4*)(out + rowB * D_FEAT + 4 * ql) = v;
            }
        }
        #undef GH4
    } else {
        for (int r = w; r < RPB; r += 4) {
            const int row = b * RPB + r;
            if (row < n_rows) out[row * D_FEAT + lane] = 0.0f;
        }
        __syncthreads();
        for (int ch = w; ch < nch; ch += 4) {
            const int cbase = (ch << ch_bits) + soff16[ch];
            const int c = scnt16[ch];
            for (int k = 0; k < c; ++k) {
                const uint2 p = pairs[cbase + k];
                const int rl = (int)(p.x >> COL_BITS);
                const int cc = (int)(p.x & COL_MASK);
                const float m = __uint_as_float(p.y) *
                                __half2float(x[cc * D_FEAT + lane]);
                const int row = b * RPB + rl;
                if (row < n_rows) atomicAdd(&out[row * D_FEAT + lane], m);
            }
        }
    }
}

extern "C" void kernel_launch(void* const* d_in, const int* in_sizes, int n_in,
                              void* d_out, int out_size, void* d_ws, size_t ws_size,
                              hipStream_t stream) {
    const float* x    = (const float*)d_in[1];
    const int*   rows = (const int*)d_in[2];
    const int*   cols = (const int*)d_in[3];
    const float* ev   = (const float*)d_in[4];
    float* out = (float*)d_out;
    const int n_edges = in_sizes[3];
    const int n_rows  = out_size / D_FEAT;
    const int n_x     = in_sizes[1];
    const int n_cols  = n_x / D_FEAT;
    const int nb = (n_rows + RPB - 1) / RPB;

    int ch_bits = 0, nch = 0, use_tt = 0, use_fp16 = 0;
    size_t off_table = 0, off_tableT = 0, off_xh = 0;
    for (int cb = 12; cb <= 13 && ch_bits == 0; ++cb) {
        int nc = (n_edges + (1 << cb) - 1) >> cb;
        size_t pairs_b = ((size_t)nc << cb) * 8;
        size_t tab_b = (size_t)nc * (size_t)(nb + 1) * 2;
        if (nc <= NCH_MAX && ws_size >= pairs_b + tab_b) {
            ch_bits = cb; nch = nc;
            off_table = pairs_b;
            size_t cur = pairs_b + tab_b;
            if (ws_size >= cur + tab_b) {
                use_tt = 1;
                off_tableT = cur;
                cur += tab_b;
            }
            size_t xh_b = (size_t)n_x * 2;
            cur = (cur + 255) & ~(size_t)255;
            if (ws_size >= cur + xh_b && (n_x & 3) == 0) {
                use_fp16 = 1;
                off_xh = cur;
            }
        }
    }

    if (ch_bits == 0 || nb > NB_MAX || n_cols > (1 << COL_BITS) ||
        n_rows > (1 << COL_BITS)) {
        hipMemsetAsync(d_out, 0, (size_t)out_size * sizeof(float), stream);
        spmv_coo_kernel<<<4096, 256, 0, stream>>>(x, rows, cols, ev, out, n_edges);
        return;
    }

    uint2* pairs = (uint2*)d_ws;
    unsigned short* table  = (unsigned short*)((char*)d_ws + off_table);
    unsigned short* tableT = (unsigned short*)((char*)d_ws + off_tableT);
    __half* xh = use_fp16 ? (__half*)((char*)d_ws + off_xh) : nullptr;

    chunk_sort_kernel<<<nch, 1024, 0, stream>>>(
        rows, cols, ev, pairs, table,
        (const float4*)x, xh, n_x / 4,
        n_edges, nb, ch_bits);
    if (use_tt) {
        dim3 tg((nch + TT - 1) / TT, (nb + 1 + TT - 1) / TT);
        transpose_table_kernel<<<tg, 256, 0, stream>>>(table, tableT, nch, nb + 1);
    }
    if (use_fp16)
        sort_reduce_h4_kernel<<<nb, 256, 0, stream>>>(
            xh, pairs, table, tableT, out, n_rows, nb, nch, ch_bits, use_tt);
    else
        sort_reduce_f32_kernel<<<nb, 256, 0, stream>>>(
            x, pairs, table, tableT, out, n_rows, nb, nch, ch_bits, use_tt);
}